// Round 3
// baseline (160.607 us; speedup 1.0000x reference)
//
#include <hip/hip_runtime.h>

#define BN 2
#define QN 900
#define CN 256
#define NCAM 6
#define HF 112
#define WF 200
#define ZL 10
#define YL 128
#define XL 128
#define R 4

// ---------------------------------------------------------------------------
// Kernel A: gathers only. One block per (b,q). No LDS, no barriers.
// ---------------------------------------------------------------------------
__global__ __launch_bounds__(256) void mafs_gather(
    const float* __restrict__ rp,
    const float* __restrict__ imgf,
    const float* __restrict__ lidf,
    const float* __restrict__ l2i,
    float* __restrict__ feat_cam,   // (B*Q, C)
    float* __restrict__ feat_lid)   // (B*Q, C)
{
  const int bq  = blockIdx.x;           // 0..1799
  const int b   = bq / QN;
  const int tid = threadIdx.x;          // channel

  const float rx = rp[bq*3+0], ry = rp[bq*3+1], rz = rp[bq*3+2];
  const float ax = rx * 102.4f - 51.2f;
  const float ay = ry * 102.4f - 51.2f;
  const float az = rz * 8.0f   - 5.0f;

  // ---- camera ----
  float acc = 0.f, cnt = 0.f;
  #pragma unroll
  for (int n = 0; n < NCAM; ++n) {
    const float* M = l2i + (size_t)(b*NCAM + n)*16;
    const float c0 = M[0]*ax + M[1]*ay + M[2] *az + M[3];
    const float c1 = M[4]*ax + M[5]*ay + M[6] *az + M[7];
    const float c2 = M[8]*ax + M[9]*ay + M[10]*az + M[11];
    const float dc = fmaxf(c2, 1e-5f);
    const float u = 2.0f * (c0 / dc) / 1599.0f - 1.0f;
    const float v = 2.0f * (c1 / dc) /  899.0f - 1.0f;
    const bool valid = (u >= -1.f) && (u <= 1.f) && (v >= -1.f) && (v <= 1.f)
                       && (c2 > 1e-5f);
    if (valid) {                         // block-uniform branch
      cnt += 1.f;
      const float x = ((u + 1.f) * (float)WF - 1.f) * 0.5f;
      const float y = ((v + 1.f) * (float)HF - 1.f) * 0.5f;
      const float x0f = floorf(x), y0f = floorf(y);
      const int   x0 = (int)x0f,  y0 = (int)y0f;
      const float fx = x - x0f,   fy = y - y0f;
      const float w00 = (1.f-fx)*(1.f-fy);
      const float w10 = fx*(1.f-fy);
      const float w01 = (1.f-fx)*fy;
      const float w11 = fx*fy;
      const float* fb = imgf + ((size_t)((b*NCAM + n)*CN) + tid) * (HF*WF);
      const bool xb0 = (x0   >= 0) && (x0   < WF);
      const bool xb1 = (x0+1 >= 0) && (x0+1 < WF);
      const bool yb0 = (y0   >= 0) && (y0   < HF);
      const bool yb1 = (y0+1 >= 0) && (y0+1 < HF);
      const int i00 = y0*WF + x0;
      float sv = 0.f;
      if (xb0 && yb0) sv += w00 * fb[i00];
      if (xb1 && yb0) sv += w10 * fb[i00 + 1];
      if (xb0 && yb1) sv += w01 * fb[i00 + WF];
      if (xb1 && yb1) sv += w11 * fb[i00 + WF + 1];
      acc += sv;
    }
  }
  feat_cam[(size_t)bq * CN + tid] = acc / fmaxf(cnt, 1.f);

  // ---- lidar ----
  {
    const float x = rx * (float)XL - 0.5f;
    const float y = ry * (float)YL - 0.5f;
    const float z = rz * (float)ZL - 0.5f;
    const float x0f = floorf(x), y0f = floorf(y), z0f = floorf(z);
    const int x0 = (int)x0f, y0 = (int)y0f, z0 = (int)z0f;
    const float fx = x - x0f, fy = y - y0f, fz = z - z0f;
    const float wx[2] = {1.f-fx, fx}, wy[2] = {1.f-fy, fy}, wz[2] = {1.f-fz, fz};
    const bool xb[2] = { x0 >= 0 && x0 < XL, x0+1 >= 0 && x0+1 < XL };
    const bool yb[2] = { y0 >= 0 && y0 < YL, y0+1 >= 0 && y0+1 < YL };
    const bool zb[2] = { z0 >= 0 && z0 < ZL, z0+1 >= 0 && z0+1 < ZL };
    const float* lb = lidf + ((size_t)(b*CN) + tid) * (ZL*YL*XL);
    float sv = 0.f;
    #pragma unroll
    for (int dz = 0; dz < 2; ++dz)
      #pragma unroll
      for (int dy = 0; dy < 2; ++dy)
        #pragma unroll
        for (int dx = 0; dx < 2; ++dx)
          if (xb[dx] && yb[dy] && zb[dz]) {
            const int idx = (((z0+dz)*YL) + (y0+dy))*XL + (x0+dx);
            sv += wx[dx]*wy[dy]*wz[dz] * lb[idx];
          }
    feat_lid[(size_t)bq * CN + tid] = sv;
  }
}

// ---------------------------------------------------------------------------
// Kernel B: matvec chain, R=4 rows per block.
// ---------------------------------------------------------------------------
__global__ __launch_bounds__(256) void mafs_mlp(
    const float* __restrict__ query,
    const float* __restrict__ feat_cam,
    const float* __restrict__ feat_lid,
    const float* __restrict__ cam_w, const float* __restrict__ cam_b,
    const float* __restrict__ lid_w, const float* __restrict__ lid_b,
    const float* __restrict__ att_w1, const float* __restrict__ att_b1,
    const float* __restrict__ att_w2, const float* __restrict__ att_b2,
    const float* __restrict__ fus_w1, const float* __restrict__ fus_b1,
    const float* __restrict__ ln_g, const float* __restrict__ ln_b,
    const float* __restrict__ fus_w2, const float* __restrict__ fus_b2,
    float* __restrict__ out)
{
  const int blk = blockIdx.x;          // 0..449
  const int q0  = blk * R;
  const int tid = threadIdx.x;
  const int lane = tid & 63, wv = tid >> 6;

  __shared__ float s_q[R*CN];
  __shared__ float s_a[CN*R];
  __shared__ float s_b[CN*R];
  __shared__ float s_t[CN*R];
  __shared__ float s_w0[R], s_w1[R];
  __shared__ float s_sum[R*4], s_sq[R*4];

  #pragma unroll
  for (int r = 0; r < R; ++r) {
    s_q[r*CN + tid] = query[(size_t)(q0+r)*CN + tid];
    s_a[tid*R + r]  = feat_cam[(size_t)(q0+r)*CN + tid];
    s_b[tid*R + r]  = feat_lid[(size_t)(q0+r)*CN + tid];
  }
  __syncthreads();

  // attention gate: wave wv -> row wv
  {
    const int c = lane;
    const float* qrow = s_q + wv*CN;
    float h = att_b1[c];
    #pragma unroll 4
    for (int k = 0; k < CN; ++k) h += qrow[k] * att_w1[k*64 + c];
    h = fmaxf(h, 0.f);
    float l0 = h * att_w2[2*c], l1 = h * att_w2[2*c+1];
    #pragma unroll
    for (int o = 32; o > 0; o >>= 1) { l0 += __shfl_down(l0,o); l1 += __shfl_down(l1,o); }
    if (lane == 0) {
      l0 += att_b2[0]; l1 += att_b2[1];
      const float m  = fmaxf(l0, l1);
      const float e0 = expf(l0 - m), e1 = expf(l1 - m);
      const float inv = 1.f / (e0 + e1);
      s_w0[wv] = e0 * inv; s_w1[wv] = e1 * inv;
    }
  }
  __syncthreads();

  // cam/lidar projections
  float pc[R] = {0,0,0,0}, pl[R] = {0,0,0,0};
  #pragma unroll 4
  for (int k = 0; k < CN; ++k) {
    const float wc = cam_w[k*CN + tid];
    const float wl = lid_w[k*CN + tid];
    const float4 xc = *(const float4*)&s_a[k*R];
    const float4 xl = *(const float4*)&s_b[k*R];
    pc[0] += xc.x*wc; pc[1] += xc.y*wc; pc[2] += xc.z*wc; pc[3] += xc.w*wc;
    pl[0] += xl.x*wl; pl[1] += xl.y*wl; pl[2] += xl.z*wl; pl[3] += xl.w*wl;
  }
  const float pcb = cam_b[tid], plb = lid_b[tid];
  __syncthreads();
  #pragma unroll
  for (int r = 0; r < R; ++r) {
    s_a[tid*R + r] = s_w0[r] * (pc[r] + pcb);
    s_b[tid*R + r] = s_w1[r] * (pl[r] + plb);
  }
  __syncthreads();

  // fusion layer 1 (512 -> 256)
  float t1[R] = {0,0,0,0};
  #pragma unroll 2
  for (int k = 0; k < CN; ++k) {
    const float wA = fus_w1[k*CN + tid];
    const float wB = fus_w1[(size_t)(CN + k)*CN + tid];
    const float4 xa = *(const float4*)&s_a[k*R];
    const float4 xb = *(const float4*)&s_b[k*R];
    t1[0] += xa.x*wA + xb.x*wB;
    t1[1] += xa.y*wA + xb.y*wB;
    t1[2] += xa.z*wA + xb.z*wB;
    t1[3] += xa.w*wA + xb.w*wB;
  }
  {
    const float bb = fus_b1[tid];
    #pragma unroll
    for (int r = 0; r < R; ++r) t1[r] += bb;
  }

  // layer norm + relu
  #pragma unroll
  for (int r = 0; r < R; ++r) {
    float s1 = t1[r];
    #pragma unroll
    for (int o = 32; o > 0; o >>= 1) s1 += __shfl_down(s1, o);
    if (lane == 0) s_sum[r*4 + wv] = s1;
  }
  __syncthreads();
  float mu[R];
  #pragma unroll
  for (int r = 0; r < R; ++r)
    mu[r] = (s_sum[r*4+0] + s_sum[r*4+1] + s_sum[r*4+2] + s_sum[r*4+3]) * (1.f/256.f);
  #pragma unroll
  for (int r = 0; r < R; ++r) {
    const float d = t1[r] - mu[r];
    float s2 = d * d;
    #pragma unroll
    for (int o = 32; o > 0; o >>= 1) s2 += __shfl_down(s2, o);
    if (lane == 0) s_sq[r*4 + wv] = s2;
  }
  __syncthreads();
  {
    const float g = ln_g[tid], be = ln_b[tid];
    #pragma unroll
    for (int r = 0; r < R; ++r) {
      const float var = (s_sq[r*4+0] + s_sq[r*4+1] + s_sq[r*4+2] + s_sq[r*4+3]) * (1.f/256.f);
      const float ri = rsqrtf(var + 1e-5f);
      s_t[tid*R + r] = fmaxf((t1[r] - mu[r]) * ri * g + be, 0.f);
    }
  }
  __syncthreads();

  // output projection
  float o[R] = {0,0,0,0};
  #pragma unroll 4
  for (int k = 0; k < CN; ++k) {
    const float w = fus_w2[k*CN + tid];
    const float4 xt = *(const float4*)&s_t[k*R];
    o[0] += xt.x*w; o[1] += xt.y*w; o[2] += xt.z*w; o[3] += xt.w*w;
  }
  const float ob = fus_b2[tid];
  #pragma unroll
  for (int r = 0; r < R; ++r)
    out[(size_t)(q0+r)*CN + tid] = o[r] + ob;
}

// ---------------------------------------------------------------------------
// Fallback: round-2 fused kernel (used only if ws_size is too small).
// ---------------------------------------------------------------------------
__global__ __launch_bounds__(256) void mafs_fused_fb(
    const float* __restrict__ query,
    const float* __restrict__ rp,
    const float* __restrict__ imgf,
    const float* __restrict__ lidf,
    const float* __restrict__ l2i,
    const float* __restrict__ cam_w, const float* __restrict__ cam_b,
    const float* __restrict__ lid_w, const float* __restrict__ lid_b,
    const float* __restrict__ att_w1, const float* __restrict__ att_b1,
    const float* __restrict__ att_w2, const float* __restrict__ att_b2,
    const float* __restrict__ fus_w1, const float* __restrict__ fus_b1,
    const float* __restrict__ ln_g, const float* __restrict__ ln_b,
    const float* __restrict__ fus_w2, const float* __restrict__ fus_b2,
    float* __restrict__ out)
{
  const int blk = blockIdx.x;
  const int q0  = blk * R;
  const int b   = q0 / QN;
  const int tid = threadIdx.x;
  const int lane = tid & 63, wv = tid >> 6;

  __shared__ float s_q[R*CN];
  __shared__ float s_a[CN*R];
  __shared__ float s_b[CN*R];
  __shared__ float s_t[CN*R];
  __shared__ float s_w0[R], s_w1[R];
  __shared__ float s_sum[R*4], s_sq[R*4];

  #pragma unroll
  for (int r = 0; r < R; ++r)
    s_q[r*CN + tid] = query[(size_t)(q0+r)*CN + tid];
  __syncthreads();

  {
    const int c = lane;
    const float* qrow = s_q + wv*CN;
    float h = att_b1[c];
    #pragma unroll 4
    for (int k = 0; k < CN; ++k) h += qrow[k] * att_w1[k*64 + c];
    h = fmaxf(h, 0.f);
    float l0 = h * att_w2[2*c], l1 = h * att_w2[2*c+1];
    #pragma unroll
    for (int o = 32; o > 0; o >>= 1) { l0 += __shfl_down(l0,o); l1 += __shfl_down(l1,o); }
    if (lane == 0) {
      l0 += att_b2[0]; l1 += att_b2[1];
      const float m  = fmaxf(l0, l1);
      const float e0 = expf(l0 - m), e1 = expf(l1 - m);
      const float inv = 1.f / (e0 + e1);
      s_w0[wv] = e0 * inv; s_w1[wv] = e1 * inv;
    }
  }

  float ax[R], ay[R], az[R], rxx[R], ryy[R], rzz[R];
  #pragma unroll
  for (int r = 0; r < R; ++r) {
    const int bq = q0 + r;
    const float rx = rp[bq*3+0], ry = rp[bq*3+1], rz = rp[bq*3+2];
    rxx[r] = rx; ryy[r] = ry; rzz[r] = rz;
    ax[r] = rx * 102.4f - 51.2f;
    ay[r] = ry * 102.4f - 51.2f;
    az[r] = rz * 8.0f   - 5.0f;
  }

  float fc[R] = {0.f,0.f,0.f,0.f}, cnt[R] = {0.f,0.f,0.f,0.f};
  #pragma unroll
  for (int n = 0; n < NCAM; ++n) {
    const float* M = l2i + (size_t)(b*NCAM + n)*16;
    const float m0=M[0],m1=M[1],m2=M[2],m3=M[3];
    const float m4=M[4],m5=M[5],m6=M[6],m7=M[7];
    const float m8=M[8],m9=M[9],m10=M[10],m11=M[11];
    #pragma unroll
    for (int r = 0; r < R; ++r) {
      const float c0 = m0*ax[r] + m1*ay[r] + m2 *az[r] + m3;
      const float c1 = m4*ax[r] + m5*ay[r] + m6 *az[r] + m7;
      const float c2 = m8*ax[r] + m9*ay[r] + m10*az[r] + m11;
      const float dc = fmaxf(c2, 1e-5f);
      const float u = 2.0f * (c0 / dc) / 1599.0f - 1.0f;
      const float v = 2.0f * (c1 / dc) /  899.0f - 1.0f;
      const bool valid = (u >= -1.f) && (u <= 1.f) && (v >= -1.f) && (v <= 1.f)
                         && (c2 > 1e-5f);
      if (valid) {
        cnt[r] += 1.f;
        const float x = ((u + 1.f) * (float)WF - 1.f) * 0.5f;
        const float y = ((v + 1.f) * (float)HF - 1.f) * 0.5f;
        const float x0f = floorf(x), y0f = floorf(y);
        const int   x0 = (int)x0f,  y0 = (int)y0f;
        const float fx = x - x0f,   fy = y - y0f;
        const float w00 = (1.f-fx)*(1.f-fy);
        const float w10 = fx*(1.f-fy);
        const float w01 = (1.f-fx)*fy;
        const float w11 = fx*fy;
        const float* fb = imgf + ((size_t)((b*NCAM + n)*CN) + tid) * (HF*WF);
        const bool xb0 = (x0   >= 0) && (x0   < WF);
        const bool xb1 = (x0+1 >= 0) && (x0+1 < WF);
        const bool yb0 = (y0   >= 0) && (y0   < HF);
        const bool yb1 = (y0+1 >= 0) && (y0+1 < HF);
        const int i00 = y0*WF + x0;
        float sv = 0.f;
        if (xb0 && yb0) sv += w00 * fb[i00];
        if (xb1 && yb0) sv += w10 * fb[i00 + 1];
        if (xb0 && yb1) sv += w01 * fb[i00 + WF];
        if (xb1 && yb1) sv += w11 * fb[i00 + WF + 1];
        fc[r] += sv;
      }
    }
  }
  #pragma unroll
  for (int r = 0; r < R; ++r) fc[r] /= fmaxf(cnt[r], 1.f);

  float fl[R];
  #pragma unroll
  for (int r = 0; r < R; ++r) {
    const float x = rxx[r] * (float)XL - 0.5f;
    const float y = ryy[r] * (float)YL - 0.5f;
    const float z = rzz[r] * (float)ZL - 0.5f;
    const float x0f = floorf(x), y0f = floorf(y), z0f = floorf(z);
    const int x0 = (int)x0f, y0 = (int)y0f, z0 = (int)z0f;
    const float fx = x - x0f, fy = y - y0f, fz = z - z0f;
    const float wx[2] = {1.f-fx, fx}, wy[2] = {1.f-fy, fy}, wz[2] = {1.f-fz, fz};
    const bool xb[2] = { x0 >= 0 && x0 < XL, x0+1 >= 0 && x0+1 < XL };
    const bool yb[2] = { y0 >= 0 && y0 < YL, y0+1 >= 0 && y0+1 < YL };
    const bool zb[2] = { z0 >= 0 && z0 < ZL, z0+1 >= 0 && z0+1 < ZL };
    const float* lb = lidf + ((size_t)(b*CN) + tid) * (ZL*YL*XL);
    float sv = 0.f;
    #pragma unroll
    for (int dz = 0; dz < 2; ++dz)
      #pragma unroll
      for (int dy = 0; dy < 2; ++dy)
        #pragma unroll
        for (int dx = 0; dx < 2; ++dx)
          if (xb[dx] && yb[dy] && zb[dz]) {
            const int idx = (((z0+dz)*YL) + (y0+dy))*XL + (x0+dx);
            sv += wx[dx]*wy[dy]*wz[dz] * lb[idx];
          }
    fl[r] = sv;
  }

  #pragma unroll
  for (int r = 0; r < R; ++r) { s_a[tid*R + r] = fc[r]; s_b[tid*R + r] = fl[r]; }
  __syncthreads();

  float pc[R] = {0,0,0,0}, pl[R] = {0,0,0,0};
  #pragma unroll 4
  for (int k = 0; k < CN; ++k) {
    const float wc = cam_w[k*CN + tid];
    const float wl = lid_w[k*CN + tid];
    const float4 xc = *(const float4*)&s_a[k*R];
    const float4 xl = *(const float4*)&s_b[k*R];
    pc[0] += xc.x*wc; pc[1] += xc.y*wc; pc[2] += xc.z*wc; pc[3] += xc.w*wc;
    pl[0] += xl.x*wl; pl[1] += xl.y*wl; pl[2] += xl.z*wl; pl[3] += xl.w*wl;
  }
  const float pcb = cam_b[tid], plb = lid_b[tid];
  __syncthreads();
  #pragma unroll
  for (int r = 0; r < R; ++r) {
    s_a[tid*R + r] = s_w0[r] * (pc[r] + pcb);
    s_b[tid*R + r] = s_w1[r] * (pl[r] + plb);
  }
  __syncthreads();

  float t1[R] = {0,0,0,0};
  #pragma unroll 2
  for (int k = 0; k < CN; ++k) {
    const float wA = fus_w1[k*CN + tid];
    const float wB = fus_w1[(size_t)(CN + k)*CN + tid];
    const float4 xa = *(const float4*)&s_a[k*R];
    const float4 xb = *(const float4*)&s_b[k*R];
    t1[0] += xa.x*wA + xb.x*wB;
    t1[1] += xa.y*wA + xb.y*wB;
    t1[2] += xa.z*wA + xb.z*wB;
    t1[3] += xa.w*wA + xb.w*wB;
  }
  {
    const float bb = fus_b1[tid];
    #pragma unroll
    for (int r = 0; r < R; ++r) t1[r] += bb;
  }

  #pragma unroll
  for (int r = 0; r < R; ++r) {
    float s1 = t1[r];
    #pragma unroll
    for (int o = 32; o > 0; o >>= 1) s1 += __shfl_down(s1, o);
    if (lane == 0) s_sum[r*4 + wv] = s1;
  }
  __syncthreads();
  float mu[R];
  #pragma unroll
  for (int r = 0; r < R; ++r)
    mu[r] = (s_sum[r*4+0] + s_sum[r*4+1] + s_sum[r*4+2] + s_sum[r*4+3]) * (1.f/256.f);
  #pragma unroll
  for (int r = 0; r < R; ++r) {
    const float d = t1[r] - mu[r];
    float s2 = d * d;
    #pragma unroll
    for (int o = 32; o > 0; o >>= 1) s2 += __shfl_down(s2, o);
    if (lane == 0) s_sq[r*4 + wv] = s2;
  }
  __syncthreads();
  {
    const float g = ln_g[tid], be = ln_b[tid];
    #pragma unroll
    for (int r = 0; r < R; ++r) {
      const float var = (s_sq[r*4+0] + s_sq[r*4+1] + s_sq[r*4+2] + s_sq[r*4+3]) * (1.f/256.f);
      const float ri = rsqrtf(var + 1e-5f);
      s_t[tid*R + r] = fmaxf((t1[r] - mu[r]) * ri * g + be, 0.f);
    }
  }
  __syncthreads();

  float o[R] = {0,0,0,0};
  #pragma unroll 4
  for (int k = 0; k < CN; ++k) {
    const float w = fus_w2[k*CN + tid];
    const float4 xt = *(const float4*)&s_t[k*R];
    o[0] += xt.x*w; o[1] += xt.y*w; o[2] += xt.z*w; o[3] += xt.w*w;
  }
  const float ob = fus_b2[tid];
  #pragma unroll
  for (int r = 0; r < R; ++r)
    out[(size_t)(q0+r)*CN + tid] = o[r] + ob;
}

extern "C" void kernel_launch(void* const* d_in, const int* in_sizes, int n_in,
                              void* d_out, int out_size, void* d_ws, size_t ws_size,
                              hipStream_t stream) {
  const float* query   = (const float*)d_in[0];
  const float* rpts    = (const float*)d_in[1];
  const float* imgf    = (const float*)d_in[2];
  const float* lidf    = (const float*)d_in[3];
  const float* l2i     = (const float*)d_in[4];
  const float* cam_w   = (const float*)d_in[5];
  const float* cam_b   = (const float*)d_in[6];
  const float* lid_w   = (const float*)d_in[7];
  const float* lid_b   = (const float*)d_in[8];
  const float* att_w1  = (const float*)d_in[9];
  const float* att_b1  = (const float*)d_in[10];
  const float* att_w2  = (const float*)d_in[11];
  const float* att_b2  = (const float*)d_in[12];
  const float* fus_w1  = (const float*)d_in[13];
  const float* fus_b1  = (const float*)d_in[14];
  const float* ln_g    = (const float*)d_in[15];
  const float* ln_b    = (const float*)d_in[16];
  const float* fus_w2  = (const float*)d_in[17];
  const float* fus_b2  = (const float*)d_in[18];
  float* out = (float*)d_out;

  const size_t feat_elems = (size_t)BN * QN * CN;        // 460800
  const size_t need = 2 * feat_elems * sizeof(float);    // ~3.7 MB

  if (ws_size >= need) {
    float* feat_cam = (float*)d_ws;
    float* feat_lid = feat_cam + feat_elems;
    mafs_gather<<<dim3(BN*QN), dim3(256), 0, stream>>>(
        rpts, imgf, lidf, l2i, feat_cam, feat_lid);
    mafs_mlp<<<dim3((BN*QN)/R), dim3(256), 0, stream>>>(
        query, feat_cam, feat_lid,
        cam_w, cam_b, lid_w, lid_b,
        att_w1, att_b1, att_w2, att_b2,
        fus_w1, fus_b1, ln_g, ln_b, fus_w2, fus_b2, out);
  } else {
    mafs_fused_fb<<<dim3((BN*QN)/R), dim3(256), 0, stream>>>(
        query, rpts, imgf, lidf, l2i,
        cam_w, cam_b, lid_w, lid_b,
        att_w1, att_b1, att_w2, att_b2,
        fus_w1, fus_b1, ln_g, ln_b, fus_w2, fus_b2, out);
  }
}

// Round 4
// 118.988 us; speedup vs baseline: 1.3498x; 1.3498x over previous
//
#include <hip/hip_runtime.h>

#define QN 900
#define CN 256
#define NCAM 6
#define HF 112
#define WF 200
#define ZL 10
#define YL 128
#define XL 128
#define R 2

__global__ __launch_bounds__(256) void mafs_fused(
    const float* __restrict__ query,
    const float* __restrict__ rp,
    const float* __restrict__ imgf,
    const float* __restrict__ lidf,
    const float* __restrict__ l2i,
    const float* __restrict__ cam_w, const float* __restrict__ cam_b,
    const float* __restrict__ lid_w, const float* __restrict__ lid_b,
    const float* __restrict__ att_w1, const float* __restrict__ att_b1,
    const float* __restrict__ att_w2, const float* __restrict__ att_b2,
    const float* __restrict__ fus_w1, const float* __restrict__ fus_b1,
    const float* __restrict__ ln_g, const float* __restrict__ ln_b,
    const float* __restrict__ fus_w2, const float* __restrict__ fus_b2,
    float* __restrict__ out)
{
  const int blk = blockIdx.x;          // 0..899
  const int q0  = blk * R;             // rows q0, q0+1 (same batch: 900 even)
  const int b   = q0 / QN;
  const int tid = threadIdx.x;         // channel
  const int lane = tid & 63, wv = tid >> 6;

  __shared__ float s_q[R*CN];
  __shared__ float s_a[CN*R], s_b[CN*R], s_t[CN*R];
  __shared__ float s_hp[4*64];
  __shared__ float s_w0[R], s_w1[R];
  __shared__ float s_red[16];          // [0..7]=sums, [8..15]=sqsums

  // ---- stage query rows ----
  #pragma unroll
  for (int r = 0; r < R; ++r)
    s_q[r*CN + tid] = query[(size_t)(q0+r)*CN + tid];
  __syncthreads();

  // ---- attention gate, split across all 4 waves: row = wv&1, k-half = wv>>1 ----
  {
    const int r  = wv & 1;
    const int kh = wv >> 1;
    const float* qrow = s_q + r*CN + kh*128;
    const float* w1p  = att_w1 + (size_t)kh*128*64;
    float h = 0.f;
    #pragma unroll 4
    for (int k = 0; k < 128; ++k) h += qrow[k] * w1p[k*64 + lane];
    s_hp[wv*64 + lane] = h;
  }
  __syncthreads();
  if (wv < R) {
    const int r = wv;
    float h = s_hp[r*64 + lane] + s_hp[(r+2)*64 + lane] + att_b1[lane];
    h = fmaxf(h, 0.f);
    float l0 = h * att_w2[2*lane], l1 = h * att_w2[2*lane+1];
    #pragma unroll
    for (int o = 32; o > 0; o >>= 1) { l0 += __shfl_down(l0,o); l1 += __shfl_down(l1,o); }
    if (lane == 0) {
      l0 += att_b2[0]; l1 += att_b2[1];
      const float m  = fmaxf(l0, l1);
      const float e0 = expf(l0 - m), e1 = expf(l1 - m);
      const float inv = 1.f / (e0 + e1);
      s_w0[r] = e0 * inv; s_w1[r] = e1 * inv;
    }
  }
  // (no barrier here: s_w0/s_w1 consumed after the post-gather barrier)

  // ---- reference points ----
  float rxx[R], ryy[R], rzz[R];
  #pragma unroll
  for (int r = 0; r < R; ++r) {
    rxx[r] = rp[(q0+r)*3+0];
    ryy[r] = rp[(q0+r)*3+1];
    rzz[r] = rp[(q0+r)*3+2];
  }

  // ---- LIDAR: issue all 16 loads branchless, consume later ----
  float lv[R][8], lw[R][8];
  {
    const float* lbase = lidf + ((size_t)(b*CN) + tid) * (ZL*YL*XL);
    #pragma unroll
    for (int r = 0; r < R; ++r) {
      const float x = rxx[r]*(float)XL - 0.5f;
      const float y = ryy[r]*(float)YL - 0.5f;
      const float z = rzz[r]*(float)ZL - 0.5f;
      const float x0f = floorf(x), y0f = floorf(y), z0f = floorf(z);
      const int x0=(int)x0f, y0=(int)y0f, z0=(int)z0f;
      const float fx=x-x0f, fy=y-y0f, fz=z-z0f;
      const float wx[2]={1.f-fx,fx}, wy[2]={1.f-fy,fy}, wz[2]={1.f-fz,fz};
      #pragma unroll
      for (int dz = 0; dz < 2; ++dz)
        #pragma unroll
        for (int dy = 0; dy < 2; ++dy)
          #pragma unroll
          for (int dx = 0; dx < 2; ++dx) {
            const int xi=x0+dx, yi=y0+dy, zi=z0+dz;
            const bool ib = (xi>=0)&&(xi<XL)&&(yi>=0)&&(yi<YL)&&(zi>=0)&&(zi<ZL);
            const int xc=min(max(xi,0),XL-1);
            const int yc=min(max(yi,0),YL-1);
            const int zc=min(max(zi,0),ZL-1);
            const int i=(dz*2+dy)*2+dx;
            lv[r][i] = lbase[(zc*YL+yc)*XL+xc];
            lw[r][i] = ib ? wx[dx]*wy[dy]*wz[dz] : 0.f;
          }
    }
  }

  // ---- CAMERA: per-(cam,row) uniform branch, clamp+masked-weight taps ----
  float fc[R] = {0.f,0.f}, cnt[R] = {0.f,0.f};
  #pragma unroll
  for (int n = 0; n < NCAM; ++n) {
    const float* M = l2i + (size_t)(b*NCAM + n)*16;
    const float m0=M[0],m1=M[1],m2=M[2],m3=M[3];
    const float m4=M[4],m5=M[5],m6=M[6],m7=M[7];
    const float m8=M[8],m9=M[9],m10=M[10],m11=M[11];
    #pragma unroll
    for (int r = 0; r < R; ++r) {
      const float ax = rxx[r]*102.4f - 51.2f;
      const float ay = ryy[r]*102.4f - 51.2f;
      const float az = rzz[r]*8.0f   - 5.0f;
      const float c0 = m0*ax + m1*ay + m2 *az + m3;
      const float c1 = m4*ax + m5*ay + m6 *az + m7;
      const float c2 = m8*ax + m9*ay + m10*az + m11;
      const float dc = fmaxf(c2, 1e-5f);
      const float u = 2.0f * (c0 / dc) / 1599.0f - 1.0f;
      const float v = 2.0f * (c1 / dc) /  899.0f - 1.0f;
      const bool valid = (u >= -1.f) && (u <= 1.f) && (v >= -1.f) && (v <= 1.f)
                         && (c2 > 1e-5f);
      if (valid) {                      // block-uniform
        cnt[r] += 1.f;
        const float x = ((u + 1.f)*(float)WF - 1.f)*0.5f;
        const float y = ((v + 1.f)*(float)HF - 1.f)*0.5f;
        const float x0f = floorf(x), y0f = floorf(y);
        const int x0=(int)x0f, y0=(int)y0f;
        const float fx=x-x0f, fy=y-y0f;
        const bool xb0=(x0>=0)&&(x0<WF), xb1=(x0+1<WF)&&(x0+1>=0);
        const bool yb0=(y0>=0)&&(y0<HF), yb1=(y0+1<HF)&&(y0+1>=0);
        const float w00 = (xb0&&yb0) ? (1.f-fx)*(1.f-fy) : 0.f;
        const float w10 = (xb1&&yb0) ? fx*(1.f-fy)       : 0.f;
        const float w01 = (xb0&&yb1) ? (1.f-fx)*fy       : 0.f;
        const float w11 = (xb1&&yb1) ? fx*fy             : 0.f;
        const int xc0=min(max(x0,0),WF-1),  xc1=min(max(x0+1,0),WF-1);
        const int yc0=min(max(y0,0),HF-1),  yc1=min(max(y0+1,0),HF-1);
        const float* fb = imgf + ((size_t)((b*NCAM + n)*CN) + tid)*(HF*WF);
        const float t00 = fb[yc0*WF + xc0];
        const float t10 = fb[yc0*WF + xc1];
        const float t01 = fb[yc1*WF + xc0];
        const float t11 = fb[yc1*WF + xc1];
        fc[r] += w00*t00 + w10*t10 + w01*t01 + w11*t11;
      }
    }
  }
  #pragma unroll
  for (int r = 0; r < R; ++r) fc[r] /= fmaxf(cnt[r], 1.f);

  // ---- consume lidar loads (they've been in flight through the cam phase) ----
  float fl[R];
  #pragma unroll
  for (int r = 0; r < R; ++r) {
    float s = 0.f;
    #pragma unroll
    for (int i = 0; i < 8; ++i) s += lw[r][i] * lv[r][i];
    fl[r] = s;
  }

  #pragma unroll
  for (int r = 0; r < R; ++r) { s_a[tid*R + r] = fc[r]; s_b[tid*R + r] = fl[r]; }
  __syncthreads();

  // ---- cam/lidar projections ----
  float pc[R] = {0,0}, pl[R] = {0,0};
  #pragma unroll 4
  for (int k = 0; k < CN; ++k) {
    const float wc = cam_w[k*CN + tid];
    const float wl = lid_w[k*CN + tid];
    const float2 xa = *(const float2*)&s_a[k*R];
    const float2 xb = *(const float2*)&s_b[k*R];
    pc[0] += xa.x*wc; pc[1] += xa.y*wc;
    pl[0] += xb.x*wl; pl[1] += xb.y*wl;
  }
  const float pcb = cam_b[tid], plb = lid_b[tid];
  __syncthreads();
  #pragma unroll
  for (int r = 0; r < R; ++r) {
    s_a[tid*R + r] = s_w0[r] * (pc[r] + pcb);
    s_b[tid*R + r] = s_w1[r] * (pl[r] + plb);
  }
  __syncthreads();

  // ---- fusion layer 1 (512 -> 256) ----
  float t1[R] = {0,0};
  #pragma unroll 2
  for (int k = 0; k < CN; ++k) {
    const float wA = fus_w1[k*CN + tid];
    const float wB = fus_w1[(size_t)(CN + k)*CN + tid];
    const float2 xa = *(const float2*)&s_a[k*R];
    const float2 xb = *(const float2*)&s_b[k*R];
    t1[0] += xa.x*wA + xb.x*wB;
    t1[1] += xa.y*wA + xb.y*wB;
  }
  {
    const float bb = fus_b1[tid];
    t1[0] += bb; t1[1] += bb;
  }

  // ---- layer norm + relu ----
  #pragma unroll
  for (int r = 0; r < R; ++r) {
    float s1 = t1[r];
    #pragma unroll
    for (int o = 32; o > 0; o >>= 1) s1 += __shfl_down(s1, o);
    if (lane == 0) s_red[r*4 + wv] = s1;
  }
  __syncthreads();
  float mu[R];
  #pragma unroll
  for (int r = 0; r < R; ++r)
    mu[r] = (s_red[r*4+0]+s_red[r*4+1]+s_red[r*4+2]+s_red[r*4+3]) * (1.f/256.f);
  #pragma unroll
  for (int r = 0; r < R; ++r) {
    const float d = t1[r] - mu[r];
    float s2 = d*d;
    #pragma unroll
    for (int o = 32; o > 0; o >>= 1) s2 += __shfl_down(s2, o);
    if (lane == 0) s_red[8 + r*4 + wv] = s2;
  }
  __syncthreads();
  {
    const float g = ln_g[tid], be = ln_b[tid];
    #pragma unroll
    for (int r = 0; r < R; ++r) {
      const float var = (s_red[8+r*4+0]+s_red[8+r*4+1]+s_red[8+r*4+2]+s_red[8+r*4+3]) * (1.f/256.f);
      const float ri = rsqrtf(var + 1e-5f);
      s_t[tid*R + r] = fmaxf((t1[r] - mu[r]) * ri * g + be, 0.f);
    }
  }
  __syncthreads();

  // ---- output projection ----
  float o[R] = {0,0};
  #pragma unroll 4
  for (int k = 0; k < CN; ++k) {
    const float w = fus_w2[k*CN + tid];
    const float2 xt = *(const float2*)&s_t[k*R];
    o[0] += xt.x*w; o[1] += xt.y*w;
  }
  const float ob = fus_b2[tid];
  #pragma unroll
  for (int r = 0; r < R; ++r)
    out[(size_t)(q0+r)*CN + tid] = o[r] + ob;
}

extern "C" void kernel_launch(void* const* d_in, const int* in_sizes, int n_in,
                              void* d_out, int out_size, void* d_ws, size_t ws_size,
                              hipStream_t stream) {
  const float* query   = (const float*)d_in[0];
  const float* rpts    = (const float*)d_in[1];
  const float* imgf    = (const float*)d_in[2];
  const float* lidf    = (const float*)d_in[3];
  const float* l2i     = (const float*)d_in[4];
  const float* cam_w   = (const float*)d_in[5];
  const float* cam_b   = (const float*)d_in[6];
  const float* lid_w   = (const float*)d_in[7];
  const float* lid_b   = (const float*)d_in[8];
  const float* att_w1  = (const float*)d_in[9];
  const float* att_b1  = (const float*)d_in[10];
  const float* att_w2  = (const float*)d_in[11];
  const float* att_b2  = (const float*)d_in[12];
  const float* fus_w1  = (const float*)d_in[13];
  const float* fus_b1  = (const float*)d_in[14];
  const float* ln_g    = (const float*)d_in[15];
  const float* ln_b    = (const float*)d_in[16];
  const float* fus_w2  = (const float*)d_in[17];
  const float* fus_b2  = (const float*)d_in[18];
  float* out = (float*)d_out;

  dim3 grid((2*QN)/R);   // 900
  dim3 block(256);
  mafs_fused<<<grid, block, 0, stream>>>(
      query, rpts, imgf, lidf, l2i,
      cam_w, cam_b, lid_w, lid_b,
      att_w1, att_b1, att_w2, att_b2,
      fus_w1, fus_b1, ln_g, ln_b, fus_w2, fus_b2, out);
}

// Round 5
// 95.890 us; speedup vs baseline: 1.6749x; 1.2409x over previous
//
#include <hip/hip_runtime.h>

#define QN 900
#define CN 256
#define NCAM 6
#define HF 112
#define WF 200
#define ZL 10
#define YL 128
#define XL 128
#define R 4
#define NT 512

__global__ __launch_bounds__(NT, 4) void mafs_fused(
    const float* __restrict__ query,
    const float* __restrict__ rp,
    const float* __restrict__ imgf,
    const float* __restrict__ lidf,
    const float* __restrict__ l2i,
    const float* __restrict__ cam_w, const float* __restrict__ cam_b,
    const float* __restrict__ lid_w, const float* __restrict__ lid_b,
    const float* __restrict__ att_w1, const float* __restrict__ att_b1,
    const float* __restrict__ att_w2, const float* __restrict__ att_b2,
    const float* __restrict__ fus_w1, const float* __restrict__ fus_b1,
    const float* __restrict__ ln_g, const float* __restrict__ ln_b,
    const float* __restrict__ fus_w2, const float* __restrict__ fus_b2,
    float* __restrict__ out)
{
  const int blk = blockIdx.x;            // 0..449
  const int q0  = blk * R;               // 4 rows, same batch (900 % 4 == 0)
  const int b   = q0 / QN;
  const int tid = threadIdx.x;
  const int c    = tid & 255;            // channel
  const int h    = tid >> 8;             // row-pair owner: rows {2h, 2h+1}
  const int lane = tid & 63;
  const int w    = tid >> 6;             // wave 0..7

  __shared__ float s_q[R*CN];
  __shared__ float s_a[CN*R], s_b[CN*R], s_t[CN*R];
  __shared__ float s_hp[8*64];
  __shared__ float s_w0[R], s_w1[R];
  __shared__ float s_red[2*R*4];

  // ---- stage 4 query rows (coalesced) ----
  #pragma unroll
  for (int i = 0; i < 2; ++i)
    s_q[i*NT + tid] = query[(size_t)q0*CN + i*NT + tid];
  __syncthreads();

  // ---- attention gate partials: wave w -> row w&3, k-half w>>2 ----
  {
    const int rw = w & 3, kh = w >> 2;
    const float* qrow = s_q + rw*CN + kh*128;
    const float* w1p  = att_w1 + (size_t)(kh*128)*64;
    float hh = 0.f;
    #pragma unroll 4
    for (int k = 0; k < 128; ++k) hh += qrow[k] * w1p[k*64 + lane];
    s_hp[w*64 + lane] = hh;
  }
  __syncthreads();
  if (w < R) {
    float hh = s_hp[w*64 + lane] + s_hp[(w+4)*64 + lane] + att_b1[lane];
    hh = fmaxf(hh, 0.f);
    float l0 = hh * att_w2[2*lane], l1 = hh * att_w2[2*lane+1];
    #pragma unroll
    for (int o = 32; o > 0; o >>= 1) { l0 += __shfl_down(l0,o); l1 += __shfl_down(l1,o); }
    if (lane == 0) {
      l0 += att_b2[0]; l1 += att_b2[1];
      const float m  = fmaxf(l0, l1);
      const float e0 = expf(l0 - m), e1 = expf(l1 - m);
      const float inv = 1.f / (e0 + e1);
      s_w0[w] = e0 * inv; s_w1[w] = e1 * inv;
    }
  }
  // no barrier here: s_w0/s_w1 consumed after the post-gather barrier

  // ---- reference points for this thread's two rows ----
  float rxx[2], ryy[2], rzz[2];
  #pragma unroll
  for (int i = 0; i < 2; ++i) {
    const int r = 2*h + i;
    rxx[i] = rp[(q0+r)*3+0];
    ryy[i] = rp[(q0+r)*3+1];
    rzz[i] = rp[(q0+r)*3+2];
  }

  // ---- LIDAR: issue all 16 loads branchless, consume after camera ----
  float lv[2][8], lw_[2][8];
  {
    const float* lbase = lidf + ((size_t)(b*CN) + c) * (ZL*YL*XL);
    #pragma unroll
    for (int i = 0; i < 2; ++i) {
      const float x = rxx[i]*(float)XL - 0.5f;
      const float y = ryy[i]*(float)YL - 0.5f;
      const float z = rzz[i]*(float)ZL - 0.5f;
      const float x0f = floorf(x), y0f = floorf(y), z0f = floorf(z);
      const int x0=(int)x0f, y0=(int)y0f, z0=(int)z0f;
      const float fx=x-x0f, fy=y-y0f, fz=z-z0f;
      const float wx[2]={1.f-fx,fx}, wy[2]={1.f-fy,fy}, wz[2]={1.f-fz,fz};
      #pragma unroll
      for (int dz = 0; dz < 2; ++dz)
        #pragma unroll
        for (int dy = 0; dy < 2; ++dy)
          #pragma unroll
          for (int dx = 0; dx < 2; ++dx) {
            const int xi=x0+dx, yi=y0+dy, zi=z0+dz;
            const bool ib = (xi>=0)&&(xi<XL)&&(yi>=0)&&(yi<YL)&&(zi>=0)&&(zi<ZL);
            const int xc=min(max(xi,0),XL-1);
            const int yc=min(max(yi,0),YL-1);
            const int zc=min(max(zi,0),ZL-1);
            const int t=(dz*2+dy)*2+dx;
            lv[i][t]  = lbase[(zc*YL+yc)*XL+xc];
            lw_[i][t] = ib ? wx[dx]*wy[dy]*wz[dz] : 0.f;
          }
    }
  }

  // ---- CAMERA: wave-uniform valid branch, clamp+masked-weight taps ----
  float fc[2] = {0.f,0.f}, cnt[2] = {0.f,0.f};
  #pragma unroll
  for (int n = 0; n < NCAM; ++n) {
    const float* M = l2i + (size_t)(b*NCAM + n)*16;
    const float m0=M[0],m1=M[1],m2=M[2],m3=M[3];
    const float m4=M[4],m5=M[5],m6=M[6],m7=M[7];
    const float m8=M[8],m9=M[9],m10=M[10],m11=M[11];
    #pragma unroll
    for (int i = 0; i < 2; ++i) {
      const float ax = rxx[i]*102.4f - 51.2f;
      const float ay = ryy[i]*102.4f - 51.2f;
      const float az = rzz[i]*8.0f   - 5.0f;
      const float c0 = m0*ax + m1*ay + m2 *az + m3;
      const float c1 = m4*ax + m5*ay + m6 *az + m7;
      const float c2 = m8*ax + m9*ay + m10*az + m11;
      const float dc = fmaxf(c2, 1e-5f);
      const float u = 2.0f * (c0 / dc) / 1599.0f - 1.0f;
      const float v = 2.0f * (c1 / dc) /  899.0f - 1.0f;
      const bool valid = (u >= -1.f) && (u <= 1.f) && (v >= -1.f) && (v <= 1.f)
                         && (c2 > 1e-5f);
      if (valid) {                      // uniform within wave (h fixed per wave)
        cnt[i] += 1.f;
        const float x = ((u + 1.f)*(float)WF - 1.f)*0.5f;
        const float y = ((v + 1.f)*(float)HF - 1.f)*0.5f;
        const float x0f = floorf(x), y0f = floorf(y);
        const int x0=(int)x0f, y0=(int)y0f;
        const float fx=x-x0f, fy=y-y0f;
        const bool xb0=(x0>=0)&&(x0<WF), xb1=(x0+1<WF)&&(x0+1>=0);
        const bool yb0=(y0>=0)&&(y0<HF), yb1=(y0+1<HF)&&(y0+1>=0);
        const float w00 = (xb0&&yb0) ? (1.f-fx)*(1.f-fy) : 0.f;
        const float w10 = (xb1&&yb0) ? fx*(1.f-fy)       : 0.f;
        const float w01 = (xb0&&yb1) ? (1.f-fx)*fy       : 0.f;
        const float w11 = (xb1&&yb1) ? fx*fy             : 0.f;
        const int xc0=min(max(x0,0),WF-1),  xc1=min(max(x0+1,0),WF-1);
        const int yc0=min(max(y0,0),HF-1),  yc1=min(max(y0+1,0),HF-1);
        const float* fb = imgf + ((size_t)((b*NCAM + n)*CN) + c)*(HF*WF);
        const float t00 = fb[yc0*WF + xc0];
        const float t10 = fb[yc0*WF + xc1];
        const float t01 = fb[yc1*WF + xc0];
        const float t11 = fb[yc1*WF + xc1];
        fc[i] += w00*t00 + w10*t10 + w01*t01 + w11*t11;
      }
    }
  }
  #pragma unroll
  for (int i = 0; i < 2; ++i) fc[i] /= fmaxf(cnt[i], 1.f);

  // ---- consume lidar (loads have been in flight through camera phase) ----
  float fl[2];
  #pragma unroll
  for (int i = 0; i < 2; ++i) {
    float s = 0.f;
    #pragma unroll
    for (int t = 0; t < 8; ++t) s += lw_[i][t] * lv[i][t];
    fl[i] = s;
  }

  #pragma unroll
  for (int i = 0; i < 2; ++i) {
    s_a[c*R + 2*h + i] = fc[i];
    s_b[c*R + 2*h + i] = fl[i];
  }
  __syncthreads();

  // ---- cam/lidar projections: weight col c feeds 4 rows (2 per thread) ----
  float pc[2] = {0,0}, pl[2] = {0,0};
  #pragma unroll 8
  for (int k = 0; k < CN; ++k) {
    const float wc = cam_w[k*CN + c];
    const float wl = lid_w[k*CN + c];
    const float2 xa = *(const float2*)&s_a[k*R + 2*h];
    const float2 xb = *(const float2*)&s_b[k*R + 2*h];
    pc[0] += xa.x*wc; pc[1] += xa.y*wc;
    pl[0] += xb.x*wl; pl[1] += xb.y*wl;
  }
  const float pcb = cam_b[c], plb = lid_b[c];
  __syncthreads();
  #pragma unroll
  for (int i = 0; i < 2; ++i) {
    const int r = 2*h + i;
    s_a[c*R + r] = s_w0[r] * (pc[i] + pcb);
    s_b[c*R + r] = s_w1[r] * (pl[i] + plb);
  }
  __syncthreads();

  // ---- fusion layer 1 (512 -> 256) ----
  float t1[2] = {0,0};
  #pragma unroll 4
  for (int k = 0; k < CN; ++k) {
    const float wA = fus_w1[k*CN + c];
    const float wB = fus_w1[(size_t)(CN + k)*CN + c];
    const float2 xa = *(const float2*)&s_a[k*R + 2*h];
    const float2 xb = *(const float2*)&s_b[k*R + 2*h];
    t1[0] += xa.x*wA + xb.x*wB;
    t1[1] += xa.y*wA + xb.y*wB;
  }
  {
    const float bb = fus_b1[c];
    t1[0] += bb; t1[1] += bb;
  }

  // ---- layer norm + relu (row r reduced across the 4 waves of its h-group) ----
  #pragma unroll
  for (int i = 0; i < 2; ++i) {
    float s1 = t1[i];
    #pragma unroll
    for (int o = 32; o > 0; o >>= 1) s1 += __shfl_down(s1, o);
    if (lane == 0) s_red[(2*h+i)*4 + (w & 3)] = s1;
  }
  __syncthreads();
  float mu[2];
  #pragma unroll
  for (int i = 0; i < 2; ++i) {
    const int r = 2*h + i;
    mu[i] = (s_red[r*4+0]+s_red[r*4+1]+s_red[r*4+2]+s_red[r*4+3]) * (1.f/256.f);
  }
  #pragma unroll
  for (int i = 0; i < 2; ++i) {
    const float d = t1[i] - mu[i];
    float s2 = d*d;
    #pragma unroll
    for (int o = 32; o > 0; o >>= 1) s2 += __shfl_down(s2, o);
    if (lane == 0) s_red[16 + (2*h+i)*4 + (w & 3)] = s2;
  }
  __syncthreads();
  {
    const float g = ln_g[c], be = ln_b[c];
    #pragma unroll
    for (int i = 0; i < 2; ++i) {
      const int r = 2*h + i;
      const float var = (s_red[16+r*4+0]+s_red[16+r*4+1]+s_red[16+r*4+2]+s_red[16+r*4+3]) * (1.f/256.f);
      const float ri = rsqrtf(var + 1e-5f);
      s_t[c*R + r] = fmaxf((t1[i] - mu[i]) * ri * g + be, 0.f);
    }
  }
  __syncthreads();

  // ---- output projection (256 -> 256) ----
  float o[2] = {0,0};
  #pragma unroll 4
  for (int k = 0; k < CN; ++k) {
    const float wgt = fus_w2[k*CN + c];
    const float2 xt = *(const float2*)&s_t[k*R + 2*h];
    o[0] += xt.x*wgt; o[1] += xt.y*wgt;
  }
  const float ob = fus_b2[c];
  #pragma unroll
  for (int i = 0; i < 2; ++i)
    out[(size_t)(q0 + 2*h + i)*CN + c] = o[i] + ob;
}

extern "C" void kernel_launch(void* const* d_in, const int* in_sizes, int n_in,
                              void* d_out, int out_size, void* d_ws, size_t ws_size,
                              hipStream_t stream) {
  const float* query   = (const float*)d_in[0];
  const float* rpts    = (const float*)d_in[1];
  const float* imgf    = (const float*)d_in[2];
  const float* lidf    = (const float*)d_in[3];
  const float* l2i     = (const float*)d_in[4];
  const float* cam_w   = (const float*)d_in[5];
  const float* cam_b   = (const float*)d_in[6];
  const float* lid_w   = (const float*)d_in[7];
  const float* lid_b   = (const float*)d_in[8];
  const float* att_w1  = (const float*)d_in[9];
  const float* att_b1  = (const float*)d_in[10];
  const float* att_w2  = (const float*)d_in[11];
  const float* att_b2  = (const float*)d_in[12];
  const float* fus_w1  = (const float*)d_in[13];
  const float* fus_b1  = (const float*)d_in[14];
  const float* ln_g    = (const float*)d_in[15];
  const float* ln_b    = (const float*)d_in[16];
  const float* fus_w2  = (const float*)d_in[17];
  const float* fus_b2  = (const float*)d_in[18];
  float* out = (float*)d_out;

  dim3 grid((2*QN)/R);   // 450
  dim3 block(NT);        // 512
  mafs_fused<<<grid, block, 0, stream>>>(
      query, rpts, imgf, lidf, l2i,
      cam_w, cam_b, lid_w, lid_b,
      att_w1, att_b1, att_w2, att_b2,
      fus_w1, fus_b1, ln_g, ln_b, fus_w2, fus_b2, out);
}